// Round 2
// baseline (298.155 us; speedup 1.0000x reference)
//
#include <hip/hip_runtime.h>

#define D 128  // D_IN == D_OUT == 128 for this problem

// ---------------- GEMM: Xp = X @ W  (fp32, LDS-tiled, K-chunked) ----------------
// 64 rows per block, all 128 cols, K staged in two 64-wide chunks.
// 256 threads: tc = tid&15 -> cols tc*8..+7 ; tr = tid>>4 -> rows tr*4..+3
// LDS: Ws 32 KiB + Xs 18 KiB = 50 KiB -> 3 blocks/CU.
__global__ __launch_bounds__(256) void gemm_xw(const float* __restrict__ X,
                                               const float* __restrict__ W,
                                               float* __restrict__ Xp, int n)
{
    __shared__ float Ws[64 * D];    // W[k0..k0+63][0..127]
    __shared__ float Xs[64 * 72];   // X[r0..r0+63][k0..k0+63], row stride 72 (pad)
    const int tid = threadIdx.x;
    const int r0 = blockIdx.x * 64;
    const int tc = tid & 15, tr = tid >> 4;

    float acc[4][8];
    #pragma unroll
    for (int i = 0; i < 4; ++i)
        #pragma unroll
        for (int j = 0; j < 8; ++j) acc[i][j] = 0.f;

    for (int k0 = 0; k0 < D; k0 += 64) {
        // stage W rows k0..k0+63: 8192 floats = 2048 float4, 8 per thread, coalesced
        {
            const float4* Wg = (const float4*)(W + k0 * D);
            float4* Wl = (float4*)Ws;
            #pragma unroll
            for (int i = 0; i < 8; ++i) Wl[tid + i * 256] = Wg[tid + i * 256];
        }
        // stage X tile 64 rows x 64 k: 1024 float4, 4 per thread, coalesced
        #pragma unroll
        for (int i = 0; i < 4; ++i) {
            int f = tid + i * 256;   // 0..1023
            int row = f >> 4;        // 16 float4 per row
            int c4 = f & 15;
            float4 v = make_float4(0.f, 0.f, 0.f, 0.f);
            if (r0 + row < n) v = *(const float4*)(X + (long long)(r0 + row) * D + k0 + c4 * 4);
            *(float4*)(Xs + row * 72 + c4 * 4) = v;   // 72*4=288 B row stride, 16B aligned
        }
        __syncthreads();

        const float* xb = Xs + (tr * 4) * 72;
        const float* wb = Ws + tc * 8;
        #pragma unroll
        for (int k = 0; k < 64; k += 4) {
            float4 x[4];
            #pragma unroll
            for (int i = 0; i < 4; ++i) x[i] = *(const float4*)(xb + i * 72 + k);
            #pragma unroll
            for (int kk = 0; kk < 4; ++kk) {
                float4 wa = *(const float4*)(wb + (k + kk) * D);
                float4 wc = *(const float4*)(wb + (k + kk) * D + 4);
                float wv[8] = {wa.x, wa.y, wa.z, wa.w, wc.x, wc.y, wc.z, wc.w};
                #pragma unroll
                for (int i = 0; i < 4; ++i) {
                    float xv = ((const float*)&x[i])[kk];
                    #pragma unroll
                    for (int j = 0; j < 8; ++j) acc[i][j] += xv * wv[j];
                }
            }
        }
        __syncthreads();
    }

    #pragma unroll
    for (int i = 0; i < 4; ++i) {
        int row = r0 + tr * 4 + i;
        if (row < n) {
            float4* op = (float4*)(Xp + (long long)row * D + tc * 8);
            op[0] = make_float4(acc[i][0], acc[i][1], acc[i][2], acc[i][3]);
            op[1] = make_float4(acc[i][4], acc[i][5], acc[i][6], acc[i][7]);
        }
    }
}

// ---------------- SpMM: out[i] = deg[i] * sum_e deg[col[e]] * Xp[col[e]] ----------------
// One 64-lane wave per row; lane l holds output cols {2l, 2l+1} (float2).
// Gather per edge = 64 lanes x 8 B = 512 B contiguous (one full X' row) -> coalesced.
// NOTE: harness delivers integer inputs as int32 (NOT int64) — cast accordingly.
__global__ __launch_bounds__(256) void spmm_csr(const float* __restrict__ Xp,
                                                const float* __restrict__ deg,
                                                const int* __restrict__ rp,
                                                const int* __restrict__ ci,
                                                float* __restrict__ out, int n)
{
    const int row = (blockIdx.x << 2) + (threadIdx.x >> 6);
    if (row >= n) return;
    const int lane = threadIdx.x & 63;
    const int beg = rp[row], end = rp[row + 1];

    float ax = 0.f, ay = 0.f;
    int e = beg;
    // 2-edge unroll: independent index/degree/gather chains for latency overlap
    for (; e + 2 <= end; e += 2) {
        int c0 = ci[e], c1 = ci[e + 1];
        float d0 = deg[c0], d1 = deg[c1];
        float2 x0 = *(const float2*)(Xp + ((long long)c0 << 7) + (lane << 1));
        float2 x1 = *(const float2*)(Xp + ((long long)c1 << 7) + (lane << 1));
        ax += d0 * x0.x + d1 * x1.x;
        ay += d0 * x0.y + d1 * x1.y;
    }
    if (e < end) {
        int c0 = ci[e];
        float d0 = deg[c0];
        float2 x0 = *(const float2*)(Xp + ((long long)c0 << 7) + (lane << 1));
        ax += d0 * x0.x;
        ay += d0 * x0.y;
    }
    const float di = deg[row];
    *(float2*)(out + ((long long)row << 7) + (lane << 1)) = make_float2(di * ax, di * ay);
}

extern "C" void kernel_launch(void* const* d_in, const int* in_sizes, int n_in,
                              void* d_out, int out_size, void* d_ws, size_t ws_size,
                              hipStream_t stream)
{
    const float* X   = (const float*)d_in[0];   // [N,128] fp32
    const float* W   = (const float*)d_in[1];   // [128,128] fp32
    const float* deg = (const float*)d_in[2];   // [N] fp32
    const int*   rp  = (const int*)d_in[3];     // [N+1] int32 (harness converts int64 -> int32)
    const int*   ci  = (const int*)d_in[4];     // [E] int32
    float* out = (float*)d_out;                 // [N,128] fp32
    const int n = in_sizes[2];                  // N = 100000

    float* Xp = (float*)d_ws;  // X' = X@W : n*128 fp32 = 51.2 MB scratch

    gemm_xw<<<(n + 63) / 64, 256, 0, stream>>>(X, W, Xp, n);
    spmm_csr<<<(n + 3) / 4, 256, 0, stream>>>(Xp, deg, rp, ci, out, n);
}

// Round 3
// 204.996 us; speedup vs baseline: 1.4544x; 1.4544x over previous
//
#include <hip/hip_runtime.h>
#include <hip/hip_bf16.h>

#define D 128  // D_IN == D_OUT == 128

typedef __attribute__((ext_vector_type(8))) short bf16x8;  // 8 bf16 = 4 VGPRs
typedef __attribute__((ext_vector_type(4))) float f32x4;

static __device__ __forceinline__ ushort f2bf(float f) {
    __hip_bfloat16 h = __float2bfloat16(f);  // RNE
    return *(ushort*)&h;
}

// ---------------- W swizzle: fp32 W[128][128] -> bf16 fragment-order Wz ----------------
// Wz[((ks*8+nb)*64 + lane)*8 + j] = bf16( W[ks*32 + (lane>>4)*8 + j][nb*16 + (lane&15)] )
// so a wave's B-frag for (nb,ks) is one coalesced 16B/lane load.
__global__ __launch_bounds__(256) void swizzle_w(const float* __restrict__ W,
                                                 ushort* __restrict__ Wz)
{
    const int t = blockIdx.x * 256 + threadIdx.x;   // 0..2047 = (combo, lane)
    const int lane = t & 63;
    const int combo = t >> 6;                       // ks*8+nb, 0..31
    const int ks = combo >> 3, nb = combo & 7;
    const int krow = ks * 32 + ((lane >> 4) << 3);
    const int col  = nb * 16 + (lane & 15);
    ushort u[8];
    #pragma unroll
    for (int j = 0; j < 8; ++j) u[j] = f2bf(W[(krow + j) * D + col]);
    uint4 p;
    p.x = (uint)u[0] | ((uint)u[1] << 16);
    p.y = (uint)u[2] | ((uint)u[3] << 16);
    p.z = (uint)u[4] | ((uint)u[5] << 16);
    p.w = (uint)u[6] | ((uint)u[7] << 16);
    *(uint4*)(Wz + (size_t)t * 8) = p;
}

// ---------------- GEMM: Xp'' = bf16( deg[row] * (X @ W) ) via MFMA, no LDS ----------------
// 256 thr = 4 waves; wave w computes rows r0 = blk*64 + w*16, all 128 cols.
// A-frag: lane holds X[r0+(l&15)][ks*32 + (l>>4)*8 + 0..7]  (8 contiguous fp32 -> bf16)
// B-frag: straight 16B load from Wz (pre-swizzled)
// D: row = (l>>4)*4 + reg, col = nb*16 + (l&15)   [m89-verified mapping]
__global__ __launch_bounds__(256) void gemm_mfma(const float* __restrict__ X,
                                                 const ushort* __restrict__ Wz,
                                                 const float* __restrict__ deg,
                                                 ushort* __restrict__ Xp, int n)
{
    const int lane = threadIdx.x & 63;
    const int wave = threadIdx.x >> 6;
    const int r0 = blockIdx.x * 64 + wave * 16;
    const int m = lane & 15, quad = lane >> 4;

    long long arow = r0 + m;
    if (arow >= n) arow = n - 1;               // clamp loads; stores are guarded
    const float* xa = X + arow * D + quad * 8;

    bf16x8 afrag[4];
    #pragma unroll
    for (int ks = 0; ks < 4; ++ks) {
        float4 lo = *(const float4*)(xa + ks * 32);
        float4 hi = *(const float4*)(xa + ks * 32 + 4);
        bf16x8 a;
        a[0] = (short)f2bf(lo.x); a[1] = (short)f2bf(lo.y);
        a[2] = (short)f2bf(lo.z); a[3] = (short)f2bf(lo.w);
        a[4] = (short)f2bf(hi.x); a[5] = (short)f2bf(hi.y);
        a[6] = (short)f2bf(hi.z); a[7] = (short)f2bf(hi.w);
        afrag[ks] = a;
    }

    f32x4 acc[8];
    #pragma unroll
    for (int nb = 0; nb < 8; ++nb) acc[nb] = (f32x4){0.f, 0.f, 0.f, 0.f};

    #pragma unroll
    for (int nb = 0; nb < 8; ++nb) {
        #pragma unroll
        for (int ks = 0; ks < 4; ++ks) {
            bf16x8 b = *(const bf16x8*)(Wz + ((size_t)((ks * 8 + nb) * 64 + lane)) * 8);
            acc[nb] = __builtin_amdgcn_mfma_f32_16x16x32_bf16(afrag[ks], b, acc[nb], 0, 0, 0);
        }
    }

    // epilogue: fold deg[row] (the deg[col]-side of the symmetric norm) then bf16-store
    #pragma unroll
    for (int r = 0; r < 4; ++r) {
        const int row = r0 + quad * 4 + r;
        if (row < n) {
            const float dr = deg[row];
            #pragma unroll
            for (int nb = 0; nb < 8; ++nb)
                Xp[(size_t)row * D + nb * 16 + m] = f2bf(dr * acc[nb][r]);
        }
    }
}

// ---------------- SpMM: out[i] = deg[i] * sum_e Xp''[ci[e]]  (Xp'' bf16, pre-scaled) ----------------
// One 64-lane wave per row; lane l holds cols {2l,2l+1} packed in one uint (bf16x2).
// Gather per edge = 64 lanes x 4 B = 256 B = one full Xp'' row, coalesced.
__global__ __launch_bounds__(256) void spmm_csr(const ushort* __restrict__ Xp,
                                                const float* __restrict__ deg,
                                                const int* __restrict__ rp,
                                                const int* __restrict__ ci,
                                                float* __restrict__ out, int n)
{
    const int row = (blockIdx.x << 2) + (threadIdx.x >> 6);
    if (row >= n) return;
    const int lane = threadIdx.x & 63;
    const int beg = rp[row], end = rp[row + 1];
    const uint* Xu = (const uint*)Xp;  // row = 64 uints

    float ax = 0.f, ay = 0.f;
    int e = beg;
    // 4-edge unroll: independent index+gather chains for MLP
    for (; e + 4 <= end; e += 4) {
        int c0 = ci[e], c1 = ci[e + 1], c2 = ci[e + 2], c3 = ci[e + 3];
        uint v0 = Xu[((size_t)c0 << 6) + lane];
        uint v1 = Xu[((size_t)c1 << 6) + lane];
        uint v2 = Xu[((size_t)c2 << 6) + lane];
        uint v3 = Xu[((size_t)c3 << 6) + lane];
        ax += __uint_as_float(v0 << 16) + __uint_as_float(v1 << 16)
            + __uint_as_float(v2 << 16) + __uint_as_float(v3 << 16);
        ay += __uint_as_float(v0 & 0xffff0000u) + __uint_as_float(v1 & 0xffff0000u)
            + __uint_as_float(v2 & 0xffff0000u) + __uint_as_float(v3 & 0xffff0000u);
    }
    for (; e < end; ++e) {
        uint v = Xu[((size_t)ci[e] << 6) + lane];
        ax += __uint_as_float(v << 16);
        ay += __uint_as_float(v & 0xffff0000u);
    }
    const float di = deg[row];
    *(float2*)(out + ((size_t)row << 7) + (lane << 1)) = make_float2(di * ax, di * ay);
}

extern "C" void kernel_launch(void* const* d_in, const int* in_sizes, int n_in,
                              void* d_out, int out_size, void* d_ws, size_t ws_size,
                              hipStream_t stream)
{
    const float* X   = (const float*)d_in[0];   // [N,128] fp32
    const float* W   = (const float*)d_in[1];   // [128,128] fp32
    const float* deg = (const float*)d_in[2];   // [N] fp32
    const int*   rp  = (const int*)d_in[3];     // [N+1] int32
    const int*   ci  = (const int*)d_in[4];     // [E] int32
    float* out = (float*)d_out;                 // [N,128] fp32
    const int n = in_sizes[2];                  // N = 100000

    ushort* Xp = (ushort*)d_ws;                 // X'' bf16: n*128*2 = 25.6 MB
    ushort* Wz = Xp + (size_t)n * D;            // swizzled bf16 W: 32 KB

    swizzle_w<<<8, 256, 0, stream>>>(W, Wz);
    gemm_mfma<<<(n + 63) / 64, 256, 0, stream>>>(X, Wz, deg, Xp, n);
    spmm_csr<<<(n + 3) / 4, 256, 0, stream>>>(Xp, deg, rp, ci, out, n);
}

// Round 4
// 186.965 us; speedup vs baseline: 1.5947x; 1.0964x over previous
//
#include <hip/hip_runtime.h>
#include <hip/hip_bf16.h>

#define D 128  // D_IN == D_OUT == 128

typedef __attribute__((ext_vector_type(8))) short bf16x8;  // 8 bf16 = 4 VGPRs
typedef __attribute__((ext_vector_type(4))) float f32x4;

static __device__ __forceinline__ ushort f2bf(float f) {
    __hip_bfloat16 h = __float2bfloat16(f);  // RNE
    return *(ushort*)&h;
}
static __device__ __forceinline__ float bfl(uint u) { return __uint_as_float(u << 16); }
static __device__ __forceinline__ float bfh(uint u) { return __uint_as_float(u & 0xffff0000u); }

// ---------------- W swizzle: fp32 W[128][128] -> bf16 fragment-order Wz ----------------
// Wz[((ks*8+nb)*64 + lane)*8 + j] = bf16( W[ks*32 + (lane>>4)*8 + j][nb*16 + (lane&15)] )
__global__ __launch_bounds__(256) void swizzle_w(const float* __restrict__ W,
                                                 ushort* __restrict__ Wz)
{
    const int t = blockIdx.x * 256 + threadIdx.x;   // 0..2047 = (combo, lane)
    const int lane = t & 63;
    const int combo = t >> 6;                       // ks*8+nb, 0..31
    const int ks = combo >> 3, nb = combo & 7;
    const int krow = ks * 32 + ((lane >> 4) << 3);
    const int col  = nb * 16 + (lane & 15);
    ushort u[8];
    #pragma unroll
    for (int j = 0; j < 8; ++j) u[j] = f2bf(W[(krow + j) * D + col]);
    uint4 p;
    p.x = (uint)u[0] | ((uint)u[1] << 16);
    p.y = (uint)u[2] | ((uint)u[3] << 16);
    p.z = (uint)u[4] | ((uint)u[5] << 16);
    p.w = (uint)u[6] | ((uint)u[7] << 16);
    *(uint4*)(Wz + (size_t)t * 8) = p;
}

// ---------------- GEMM: Xp'' = bf16( deg[row] * (X @ W) ) via MFMA, no LDS ----------------
// (unchanged from R3 — isolating the spmm change this round)
__global__ __launch_bounds__(256) void gemm_mfma(const float* __restrict__ X,
                                                 const ushort* __restrict__ Wz,
                                                 const float* __restrict__ deg,
                                                 ushort* __restrict__ Xp, int n)
{
    const int lane = threadIdx.x & 63;
    const int wave = threadIdx.x >> 6;
    const int r0 = blockIdx.x * 64 + wave * 16;
    const int m = lane & 15, quad = lane >> 4;

    long long arow = r0 + m;
    if (arow >= n) arow = n - 1;               // clamp loads; stores are guarded
    const float* xa = X + arow * D + quad * 8;

    bf16x8 afrag[4];
    #pragma unroll
    for (int ks = 0; ks < 4; ++ks) {
        float4 lo = *(const float4*)(xa + ks * 32);
        float4 hi = *(const float4*)(xa + ks * 32 + 4);
        bf16x8 a;
        a[0] = (short)f2bf(lo.x); a[1] = (short)f2bf(lo.y);
        a[2] = (short)f2bf(lo.z); a[3] = (short)f2bf(lo.w);
        a[4] = (short)f2bf(hi.x); a[5] = (short)f2bf(hi.y);
        a[6] = (short)f2bf(hi.z); a[7] = (short)f2bf(hi.w);
        afrag[ks] = a;
    }

    f32x4 acc[8];
    #pragma unroll
    for (int nb = 0; nb < 8; ++nb) acc[nb] = (f32x4){0.f, 0.f, 0.f, 0.f};

    #pragma unroll
    for (int nb = 0; nb < 8; ++nb) {
        #pragma unroll
        for (int ks = 0; ks < 4; ++ks) {
            bf16x8 b = *(const bf16x8*)(Wz + ((size_t)((ks * 8 + nb) * 64 + lane)) * 8);
            acc[nb] = __builtin_amdgcn_mfma_f32_16x16x32_bf16(afrag[ks], b, acc[nb], 0, 0, 0);
        }
    }

    #pragma unroll
    for (int r = 0; r < 4; ++r) {
        const int row = r0 + quad * 4 + r;
        if (row < n) {
            const float dr = deg[row];
            #pragma unroll
            for (int nb = 0; nb < 8; ++nb)
                Xp[(size_t)row * D + nb * 16 + m] = f2bf(dr * acc[nb][r]);
        }
    }
}

// ---------------- SpMM: out[i] = deg[i] * sum_e Xp''[ci[e]]  (Xp'' bf16, pre-scaled) ----------------
// QUARTER-WAVE per row: 16 lanes/row, lane holds 8 cols via one uint4 (16 B).
// One gather instr = 4 rows x 256 B = 1 KB in flight; 4-edge unroll -> 16
// row-fetches outstanding per wave. VMEM instrs ~0.5/edge (was ~1.25/edge).
__global__ __launch_bounds__(256) void spmm_csr(const ushort* __restrict__ Xp,
                                                const float* __restrict__ deg,
                                                const int* __restrict__ rp,
                                                const int* __restrict__ ci,
                                                float* __restrict__ out, int n)
{
    const int row = blockIdx.x * 16 + (threadIdx.x >> 4);
    if (row >= n) return;
    const int sub = threadIdx.x & 15;            // lane within quarter-wave
    const int beg = rp[row], end = rp[row + 1];
    const uint4* Xq = (const uint4*)Xp;          // one bf16 row = 16 uint4

    float a0 = 0.f, a1 = 0.f, a2 = 0.f, a3 = 0.f;
    float a4 = 0.f, a5 = 0.f, a6 = 0.f, a7 = 0.f;

#define ACCUM(v)                                          \
    do {                                                  \
        a0 += bfl((v).x); a1 += bfh((v).x);               \
        a2 += bfl((v).y); a3 += bfh((v).y);               \
        a4 += bfl((v).z); a5 += bfh((v).z);               \
        a6 += bfl((v).w); a7 += bfh((v).w);               \
    } while (0)

    int e = beg;
    for (; e + 4 <= end; e += 4) {
        int c0 = ci[e], c1 = ci[e + 1], c2 = ci[e + 2], c3 = ci[e + 3];
        uint4 v0 = Xq[(size_t)c0 * 16 + sub];
        uint4 v1 = Xq[(size_t)c1 * 16 + sub];
        uint4 v2 = Xq[(size_t)c2 * 16 + sub];
        uint4 v3 = Xq[(size_t)c3 * 16 + sub];
        ACCUM(v0); ACCUM(v1); ACCUM(v2); ACCUM(v3);
    }
    for (; e < end; ++e) {
        uint4 v = Xq[(size_t)ci[e] * 16 + sub];
        ACCUM(v);
    }
#undef ACCUM

    const float dr = deg[row];
    float4* op = (float4*)(out + (size_t)row * D + sub * 8);
    op[0] = make_float4(dr * a0, dr * a1, dr * a2, dr * a3);
    op[1] = make_float4(dr * a4, dr * a5, dr * a6, dr * a7);
}

extern "C" void kernel_launch(void* const* d_in, const int* in_sizes, int n_in,
                              void* d_out, int out_size, void* d_ws, size_t ws_size,
                              hipStream_t stream)
{
    const float* X   = (const float*)d_in[0];   // [N,128] fp32
    const float* W   = (const float*)d_in[1];   // [128,128] fp32
    const float* deg = (const float*)d_in[2];   // [N] fp32
    const int*   rp  = (const int*)d_in[3];     // [N+1] int32
    const int*   ci  = (const int*)d_in[4];     // [E] int32
    float* out = (float*)d_out;                 // [N,128] fp32
    const int n = in_sizes[2];                  // N = 100000

    ushort* Xp = (ushort*)d_ws;                 // X'' bf16: n*128*2 = 25.6 MB
    ushort* Wz = Xp + (size_t)n * D;            // swizzled bf16 W: 32 KB

    swizzle_w<<<8, 256, 0, stream>>>(W, Wz);
    gemm_mfma<<<(n + 63) / 64, 256, 0, stream>>>(X, Wz, deg, Xp, n);
    spmm_csr<<<(n + 15) / 16, 256, 0, stream>>>(Xp, deg, rp, ci, out, n);
}

// Round 6
// 185.368 us; speedup vs baseline: 1.6085x; 1.0086x over previous
//
#include <hip/hip_runtime.h>
#include <hip/hip_bf16.h>

#define D 128  // D_IN == D_OUT == 128

typedef __attribute__((ext_vector_type(8))) short bf16x8;  // 8 bf16 = 4 VGPRs
typedef __attribute__((ext_vector_type(4))) float f32x4;

static __device__ __forceinline__ ushort f2bf(float f) {
    __hip_bfloat16 h = __float2bfloat16(f);  // RNE
    return *(ushort*)&h;
}
static __device__ __forceinline__ float bfl(uint u) { return __uint_as_float(u << 16); }
static __device__ __forceinline__ float bfh(uint u) { return __uint_as_float(u & 0xffff0000u); }

// ---------------- W swizzle: fp32 W[128][128] -> bf16 fragment-order Wz ----------------
// Wz[((ks*8+nb)*64 + lane)*8 + j] = bf16( W[ks*32 + (lane>>4)*8 + j][nb*16 + (lane&15)] )
__global__ __launch_bounds__(256) void swizzle_w(const float* __restrict__ W,
                                                 ushort* __restrict__ Wz)
{
    const int t = blockIdx.x * 256 + threadIdx.x;   // 0..2047 = (combo, lane)
    const int lane = t & 63;
    const int combo = t >> 6;                       // ks*8+nb, 0..31
    const int ks = combo >> 3, nb = combo & 7;
    const int krow = ks * 32 + ((lane >> 4) << 3);
    const int col  = nb * 16 + (lane & 15);
    ushort u[8];
    #pragma unroll
    for (int j = 0; j < 8; ++j) u[j] = f2bf(W[(krow + j) * D + col]);
    uint4 p;
    p.x = (uint)u[0] | ((uint)u[1] << 16);
    p.y = (uint)u[2] | ((uint)u[3] << 16);
    p.z = (uint)u[4] | ((uint)u[5] << 16);
    p.w = (uint)u[6] | ((uint)u[7] << 16);
    *(uint4*)(Wz + (size_t)t * 8) = p;
}

// ---------------- GEMM: Xp'' = bf16( deg[row] * (X @ W) ) via MFMA ----------------
// v2: Wz staged in LDS once per block (kills the 800 MB per-wave B-frag L2
// demand of v1); each wave computes 32 rows (2 M-tiles) so every ds_read_b128
// B-frag feeds 2 MFMAs. Block = 4 waves = 128 rows.
__global__ __launch_bounds__(256) void gemm_mfma(const float* __restrict__ X,
                                                 const ushort* __restrict__ Wz,
                                                 const float* __restrict__ deg,
                                                 ushort* __restrict__ Xp, int n)
{
    __shared__ ushort wsh[32 * 64 * 8];   // 32 KB, fragment-order copy of Wz
    const int tid = threadIdx.x;
    {   // stage: 2048 uint4 = 8 per thread, coalesced; lane*16B pattern
        const uint4* src = (const uint4*)Wz;
        uint4* dst = (uint4*)wsh;
        #pragma unroll
        for (int i = 0; i < 8; ++i) dst[tid + i * 256] = src[tid + i * 256];
    }
    __syncthreads();

    const int lane = tid & 63;
    const int wave = tid >> 6;
    const int m = lane & 15, quad = lane >> 4;
    const int r0 = blockIdx.x * 128 + wave * 32;   // 2 tiles: rows r0..r0+15, r0+16..r0+31

    // A-frags: lane holds X[row][ks*32 + quad*8 .. +7] as bf16x8
    bf16x8 afrag[2][4];
    #pragma unroll
    for (int t = 0; t < 2; ++t) {
        long long arow = r0 + t * 16 + m;
        if (arow >= n) arow = n - 1;               // clamp loads; stores guarded
        const float* xa = X + arow * D + quad * 8;
        #pragma unroll
        for (int ks = 0; ks < 4; ++ks) {
            float4 lo = *(const float4*)(xa + ks * 32);
            float4 hi = *(const float4*)(xa + ks * 32 + 4);
            bf16x8 a;
            a[0] = (short)f2bf(lo.x); a[1] = (short)f2bf(lo.y);
            a[2] = (short)f2bf(lo.z); a[3] = (short)f2bf(lo.w);
            a[4] = (short)f2bf(hi.x); a[5] = (short)f2bf(hi.y);
            a[6] = (short)f2bf(hi.z); a[7] = (short)f2bf(hi.w);
            afrag[t][ks] = a;
        }
    }

    f32x4 acc[2][8];
    #pragma unroll
    for (int t = 0; t < 2; ++t)
        #pragma unroll
        for (int nb = 0; nb < 8; ++nb) acc[t][nb] = (f32x4){0.f, 0.f, 0.f, 0.f};

    #pragma unroll
    for (int nb = 0; nb < 8; ++nb) {
        #pragma unroll
        for (int ks = 0; ks < 4; ++ks) {
            bf16x8 b = *(const bf16x8*)(wsh + ((size_t)((ks * 8 + nb) * 64 + lane)) * 8);
            acc[0][nb] = __builtin_amdgcn_mfma_f32_16x16x32_bf16(afrag[0][ks], b, acc[0][nb], 0, 0, 0);
            acc[1][nb] = __builtin_amdgcn_mfma_f32_16x16x32_bf16(afrag[1][ks], b, acc[1][nb], 0, 0, 0);
        }
    }

    // epilogue: fold deg[row], store bf16 (C/D map: row=quad*4+r, col=nb*16+m)
    #pragma unroll
    for (int t = 0; t < 2; ++t) {
        #pragma unroll
        for (int r = 0; r < 4; ++r) {
            const int row = r0 + t * 16 + quad * 4 + r;
            if (row < n) {
                const float dr = deg[row];
                #pragma unroll
                for (int nb = 0; nb < 8; ++nb)
                    Xp[(size_t)row * D + nb * 16 + m] = f2bf(dr * acc[t][nb][r]);
            }
        }
    }
}

// ---------------- SpMM: out[i] = deg[i] * sum_e Xp''[ci[e]]  (bf16, pre-scaled) ----------------
// (R4 known-good kernel, untouched.) Quarter-wave per row: 16 lanes/row, lane
// holds 8 cols via one uint4 (16 B). One gather instr = 4 rows x 256 B = 1 KB
// in flight; 4-edge unroll -> 4 KB outstanding per wave.
__global__ __launch_bounds__(256) void spmm_csr(const ushort* __restrict__ Xp,
                                                const float* __restrict__ deg,
                                                const int* __restrict__ rp,
                                                const int* __restrict__ ci,
                                                float* __restrict__ out, int n)
{
    const int row = blockIdx.x * 16 + (threadIdx.x >> 4);
    if (row >= n) return;
    const int sub = threadIdx.x & 15;            // lane within quarter-wave
    const int beg = rp[row], end = rp[row + 1];
    const uint4* Xq = (const uint4*)Xp;          // one bf16 row = 16 uint4

    float a0 = 0.f, a1 = 0.f, a2 = 0.f, a3 = 0.f;
    float a4 = 0.f, a5 = 0.f, a6 = 0.f, a7 = 0.f;

#define ACCUM(v)                                          \
    do {                                                  \
        a0 += bfl((v).x); a1 += bfh((v).x);               \
        a2 += bfl((v).y); a3 += bfh((v).y);               \
        a4 += bfl((v).z); a5 += bfh((v).z);               \
        a6 += bfl((v).w); a7 += bfh((v).w);               \
    } while (0)

    int e = beg;
    for (; e + 4 <= end; e += 4) {
        int c0 = ci[e], c1 = ci[e + 1], c2 = ci[e + 2], c3 = ci[e + 3];
        uint4 v0 = Xq[(size_t)c0 * 16 + sub];
        uint4 v1 = Xq[(size_t)c1 * 16 + sub];
        uint4 v2 = Xq[(size_t)c2 * 16 + sub];
        uint4 v3 = Xq[(size_t)c3 * 16 + sub];
        ACCUM(v0); ACCUM(v1); ACCUM(v2); ACCUM(v3);
    }
    for (; e < end; ++e) {
        uint4 v = Xq[(size_t)ci[e] * 16 + sub];
        ACCUM(v);
    }
#undef ACCUM

    const float dr = deg[row];
    float4* op = (float4*)(out + (size_t)row * D + sub * 8);
    op[0] = make_float4(dr * a0, dr * a1, dr * a2, dr * a3);
    op[1] = make_float4(dr * a4, dr * a5, dr * a6, dr * a7);
}

extern "C" void kernel_launch(void* const* d_in, const int* in_sizes, int n_in,
                              void* d_out, int out_size, void* d_ws, size_t ws_size,
                              hipStream_t stream)
{
    const float* X   = (const float*)d_in[0];   // [N,128] fp32
    const float* W   = (const float*)d_in[1];   // [128,128] fp32
    const float* deg = (const float*)d_in[2];   // [N] fp32
    const int*   rp  = (const int*)d_in[3];     // [N+1] int32
    const int*   ci  = (const int*)d_in[4];     // [E] int32
    float* out = (float*)d_out;                 // [N,128] fp32
    const int n = in_sizes[2];                  // N = 100000

    ushort* Xp = (ushort*)d_ws;                 // X'' bf16: n*128*2 = 25.6 MB
    ushort* Wz = Xp + (size_t)n * D;            // swizzled bf16 W: 32 KB

    swizzle_w<<<8, 256, 0, stream>>>(W, Wz);
    gemm_mfma<<<(n + 127) / 128, 256, 0, stream>>>(X, Wz, deg, Xp, n);
    spmm_csr<<<(n + 15) / 16, 256, 0, stream>>>(Xp, deg, rp, ci, out, n);
}